// Round 2
// baseline (1925.454 us; speedup 1.0000x reference)
//
#include <hip/hip_runtime.h>
#include <hip/hip_bf16.h>

#define LRELU_SLOPE 0.1f
#define KP_EXTENT 0.5f
#define NKP 15
#define NN 32
#define INF 256
#define MID 128
#define OUTF 512

__device__ __forceinline__ float lrelu(float x) { return x >= 0.f ? x : LRELU_SLOPE * x; }

// ---------------- K0: x1 = lrelu(features @ W1)  [n,256]x[256,128] ----------------
__global__ __launch_bounds__(128) void k_conv1(const float* __restrict__ feats,
                                               const float* __restrict__ W1,
                                               float* __restrict__ x1) {
  __shared__ float sf[8][INF];
  const int tid = threadIdx.x;
  const int base = blockIdx.x * 8;
#pragma unroll
  for (int r = 0; r < 8; ++r) {
    sf[r][tid]       = feats[(size_t)(base + r) * INF + tid];
    sf[r][tid + 128] = feats[(size_t)(base + r) * INF + tid + 128];
  }
  __syncthreads();
  float acc[8] = {0.f, 0.f, 0.f, 0.f, 0.f, 0.f, 0.f, 0.f};
  for (int k = 0; k < INF; ++k) {
    float w = W1[k * MID + tid];
#pragma unroll
    for (int r = 0; r < 8; ++r) acc[r] += sf[r][k] * w;
  }
#pragma unroll
  for (int r = 0; r < 8; ++r)
    x1[(size_t)(base + r) * MID + tid] = lrelu(acc[r]);
}

// ---------------- K1: per-point deformable KPConv -> x2 [n,128] ----------------
__global__ __launch_bounds__(128) void k_deform(const float* __restrict__ points,
                                                const int*  __restrict__ nbr,
                                                const float* __restrict__ x1,
                                                const float* __restrict__ Kp,
                                                const float* __restrict__ w0,
                                                const float* __restrict__ b0,
                                                const float* __restrict__ KV,
                                                float* __restrict__ x2) {
  const int i = blockIdx.x;
  const int tid = threadIdx.x;
  __shared__ float nh[NN][MID];     // gathered conv1 features
  __shared__ float wI[NKP][NN];     // influence weights
  __shared__ float wf[NKP][MID];    // weighted features per KP
  __shared__ float dpos[NN][3];     // neighbor - center
  __shared__ float dkp[NKP][3];     // deformed kernel points
  __shared__ float f0part[2][45];
  __shared__ float kpl[NKP][3];
  __shared__ int   nidx[NN];
  __shared__ float pc[3];

  if (tid < NN) nidx[tid] = nbr[(size_t)i * NN + tid];
  if (tid >= 32 && tid < 35) pc[tid - 32] = points[(size_t)i * 3 + (tid - 32)];
  if (tid >= 64 && tid < 64 + NKP * 3) {
    int t = tid - 64;
    kpl[t / 3][t % 3] = Kp[t];
  }
  __syncthreads();

  // gather neighbor features (coalesced over tid) + relative positions
  for (int j = 0; j < NN; ++j) nh[j][tid] = x1[(size_t)nidx[j] * MID + tid];
  if (tid < NN) {
    int p = nidx[tid];
    dpos[tid][0] = points[(size_t)p * 3 + 0] - pc[0];
    dpos[tid][1] = points[(size_t)p * 3 + 1] - pc[1];
    dpos[tid][2] = points[(size_t)p * 3 + 2] - pc[2];
  }
  __syncthreads();

  // influence pass 1 (rigid kernel points)
  for (int t = tid; t < NKP * NN; t += 128) {
    int k = t >> 5, j = t & 31;
    float dx = dpos[j][0] - kpl[k][0];
    float dy = dpos[j][1] - kpl[k][1];
    float dz = dpos[j][2] - kpl[k][2];
    float sq = dx * dx + dy * dy + dz * dz;
    wI[k][j] = fmaxf(1.f - sqrtf(sq) * (1.f / KP_EXTENT), 0.f);
  }
  __syncthreads();

  // wf1[k][c] = sum_j wI[k][j] * nh[j][c]
  {
    float fa[NKP];
#pragma unroll
    for (int k = 0; k < NKP; ++k) fa[k] = 0.f;
    for (int j = 0; j < NN; ++j) {
      float v = nh[j][tid];
#pragma unroll
      for (int k = 0; k < NKP; ++k) fa[k] += wI[k][j] * v;
    }
#pragma unroll
    for (int k = 0; k < NKP; ++k) wf[k][tid] = fa[k];
  }
  __syncthreads();

  // f0[o] = sum_{k,c} wf[k][c] * w0[k][c][o], split over 2 k-groups
  if (tid < 90) {
    int g = tid / 45, o = tid % 45;
    int k0 = g ? 8 : 0, k1 = g ? NKP : 8;
    float acc = 0.f;
    for (int k = k0; k < k1; ++k)
      for (int c = 0; c < MID; ++c)
        acc += wf[k][c] * w0[((size_t)(k * MID + c)) * 45 + o];
    f0part[g][o] = acc;
  }
  __syncthreads();

  // deformed kernel points
  if (tid < NKP * 3) {
    int k = tid / 3, r = tid % 3;
    float f0 = f0part[0][tid] + f0part[1][tid] + b0[tid];
    dkp[k][r] = kpl[k][r] + KP_EXTENT * f0;
  }
  __syncthreads();

  // influence pass 2 (deformed kernel points)
  for (int t = tid; t < NKP * NN; t += 128) {
    int k = t >> 5, j = t & 31;
    float dx = dpos[j][0] - dkp[k][0];
    float dy = dpos[j][1] - dkp[k][1];
    float dz = dpos[j][2] - dkp[k][2];
    float sq = dx * dx + dy * dy + dz * dz;
    wI[k][j] = fmaxf(1.f - sqrtf(sq) * (1.f / KP_EXTENT), 0.f);
  }
  __syncthreads();

  // wf2
  {
    float fa[NKP];
#pragma unroll
    for (int k = 0; k < NKP; ++k) fa[k] = 0.f;
    for (int j = 0; j < NN; ++j) {
      float v = nh[j][tid];
#pragma unroll
      for (int k = 0; k < NKP; ++k) fa[k] += wI[k][j] * v;
    }
    __syncthreads();
#pragma unroll
    for (int k = 0; k < NKP; ++k) wf[k][tid] = fa[k];
  }
  __syncthreads();

  // x2[c_out] = lrelu( sum_{k,c} wf[k][c] * KV[k][c][c_out] )
  {
    float acc = 0.f;
    for (int k = 0; k < NKP; ++k)
      for (int c = 0; c < MID; ++c)
        acc += wf[k][c] * KV[((size_t)(k * MID + c)) * MID + tid];
    x2[(size_t)i * MID + tid] = lrelu(acc);
  }
}

// ---------------- K2: out = lrelu( lrelu(f@Ws) + lrelu(x2@W3) ) ----------------
__global__ __launch_bounds__(512) void k_final(const float* __restrict__ x2,
                                               const float* __restrict__ feats,
                                               const float* __restrict__ W3,
                                               const float* __restrict__ Ws,
                                               float* __restrict__ out) {
  __shared__ float xs[4][MID];
  __shared__ float fs[4][INF];
  const int tid = threadIdx.x;
  const int base = blockIdx.x * 4;
  {
    int r = tid >> 7, c = tid & 127;
    xs[r][c] = x2[(size_t)(base + r) * MID + c];
  }
  for (int t = tid; t < 4 * INF; t += 512) {
    int r = t >> 8, c = t & 255;
    fs[r][c] = feats[(size_t)(base + r) * INF + c];
  }
  __syncthreads();
  float a3[4] = {0.f, 0.f, 0.f, 0.f};
  for (int k = 0; k < MID; ++k) {
    float w = W3[k * OUTF + tid];
#pragma unroll
    for (int r = 0; r < 4; ++r) a3[r] += xs[r][k] * w;
  }
  float as[4] = {0.f, 0.f, 0.f, 0.f};
  for (int k = 0; k < INF; ++k) {
    float w = Ws[k * OUTF + tid];
#pragma unroll
    for (int r = 0; r < 4; ++r) as[r] += fs[r][k] * w;
  }
#pragma unroll
  for (int r = 0; r < 4; ++r)
    out[(size_t)(base + r) * OUTF + tid] =
        lrelu(lrelu(as[r]) + lrelu(a3[r]));
}

extern "C" void kernel_launch(void* const* d_in, const int* in_sizes, int n_in,
                              void* d_out, int out_size, void* d_ws, size_t ws_size,
                              hipStream_t stream) {
  const float* points = (const float*)d_in[0];
  const float* feats  = (const float*)d_in[1];
  const int*   nbr    = (const int*)d_in[2];
  const float* W1     = (const float*)d_in[3];
  const float* W3     = (const float*)d_in[4];
  const float* Ws     = (const float*)d_in[5];
  const float* KV     = (const float*)d_in[6];
  const float* w0     = (const float*)d_in[7];
  const float* b0     = (const float*)d_in[8];
  const float* Kp     = (const float*)d_in[9];
  float* out = (float*)d_out;

  const int n = in_sizes[0] / 3;  // 20000
  float* x1 = (float*)d_ws;                       // [n,128] f32
  float* x2 = x1 + (size_t)n * MID;               // [n,128] f32

  k_conv1 <<<n / 8, 128, 0, stream>>>(feats, W1, x1);
  k_deform<<<n,     128, 0, stream>>>(points, nbr, x1, Kp, w0, b0, KV, x2);
  k_final <<<n / 4, 512, 0, stream>>>(x2, feats, W3, Ws, out);
}

// Round 3
// 502.447 us; speedup vs baseline: 3.8322x; 3.8322x over previous
//
#include <hip/hip_runtime.h>
#include <hip/hip_bf16.h>

#define LRELU_SLOPE 0.1f
#define KP_EXTENT 0.5f
#define NKP 15
#define NN 32
#define INF 256
#define MID 128
#define OUTF 512
#define KTOT 1920   // NKP*MID
#define KSTEPS 60   // KTOT/32

typedef unsigned short u16;
typedef unsigned int   u32;
typedef __attribute__((ext_vector_type(8))) short short8;
typedef __attribute__((ext_vector_type(4))) float f32x4;

__device__ __forceinline__ float lrelu(float x) { return x >= 0.f ? x : LRELU_SLOPE * x; }
__device__ __forceinline__ u16 f2bf(float f) {
  u32 u = __builtin_bit_cast(u32, f);
  u += 0x7fffu + ((u >> 16) & 1u);
  return (u16)(u >> 16);
}

// ---------------- K_cast: KVt[cout][kc] and w0t[o][kc] in bf16 (transposed) ----------------
__global__ __launch_bounds__(256) void k_cast(const float* __restrict__ KV,
                                              const float* __restrict__ w0,
                                              u16* __restrict__ KVt,
                                              u16* __restrict__ w0t) {
  __shared__ float tile[32][129];
  const int bx = blockIdx.x, tid = threadIdx.x;
  if (bx < 60) {                       // KV [1920][128] -> KVt [128][1920]
    const int kcb = bx * 32;
    for (int t = tid; t < 32 * 128; t += 256) {
      int kc = t >> 7, c = t & 127;
      tile[kc][c] = KV[(size_t)(kcb + kc) * 128 + c];
    }
    __syncthreads();
    for (int t = tid; t < 128 * 16; t += 256) {
      int c = t >> 4, kc = (t & 15) * 2;
      u32 pk = (u32)f2bf(tile[kc][c]) | ((u32)f2bf(tile[kc + 1][c]) << 16);
      *(u32*)(KVt + (size_t)c * KTOT + kcb + kc) = pk;
    }
  } else {                             // w0 [1920][45] -> w0t [48][1920] (pad 45..47 = 0)
    const int kcb = (bx - 60) * 32;
    for (int t = tid; t < 32 * 45; t += 256) {
      int kc = t / 45, c = t - kc * 45;
      tile[kc][c] = w0[(size_t)(kcb + kc) * 45 + c];
    }
    __syncthreads();
    for (int t = tid; t < 48 * 16; t += 256) {
      int o = t >> 4, kc = (t & 15) * 2;
      float v0 = (o < 45) ? tile[kc][o] : 0.f;
      float v1 = (o < 45) ? tile[kc + 1][o] : 0.f;
      u32 pk = (u32)f2bf(v0) | ((u32)f2bf(v1) << 16);
      *(u32*)(w0t + (size_t)o * KTOT + kcb + kc) = pk;
    }
  }
}

// ---------------- K0: x1h = bf16(lrelu(features @ W1)) ----------------
__global__ __launch_bounds__(128) void k_conv1(const float* __restrict__ feats,
                                               const float* __restrict__ W1,
                                               u16* __restrict__ x1h) {
  __shared__ float sf[8][INF];
  const int tid = threadIdx.x;
  const int base = blockIdx.x * 8;
#pragma unroll
  for (int r = 0; r < 8; ++r) {
    sf[r][tid]       = feats[(size_t)(base + r) * INF + tid];
    sf[r][tid + 128] = feats[(size_t)(base + r) * INF + tid + 128];
  }
  __syncthreads();
  float acc[8] = {0.f, 0.f, 0.f, 0.f, 0.f, 0.f, 0.f, 0.f};
  for (int k = 0; k < INF; ++k) {
    float w = W1[k * MID + tid];
#pragma unroll
    for (int r = 0; r < 8; ++r) acc[r] += sf[r][k] * w;
  }
#pragma unroll
  for (int r = 0; r < 8; ++r)
    x1h[(size_t)(base + r) * MID + tid] = f2bf(lrelu(acc[r]));
}

// ---------------- K1: deformable KPConv, 16 points/block, MFMA GEMMs ----------------
// LDS map (80384 B):
//   [0,61440)        A_lds: wf bf16, swizzled [kcg 240][slot 16][e 8], slot = p ^ (kcg&7)
//   [61440,67584)    dpos  f32 [16][32][3]
//   [67584,69632)    nidx  i32 [16][32]
//   [69632,77312)    scratch f32 1920: wI per-wave [4][480]  (aliased later: f0buf [16][48])
//   [77312,80192)    dkp   f32 [16][45]
//   [80192,80372)    kpl   f32 [45]
__global__ __launch_bounds__(256, 2) void k_deform(const float* __restrict__ points,
                                                   const int*  __restrict__ nbr,
                                                   const u16*  __restrict__ x1h,
                                                   const float* __restrict__ Kp,
                                                   const u16*  __restrict__ w0t,
                                                   const float* __restrict__ b0,
                                                   const u16*  __restrict__ KVt,
                                                   float* __restrict__ x2) {
  __shared__ __align__(16) char smem[80384];
  float (*dpos)[NN][3] = (float (*)[NN][3])(smem + 61440);
  int   (*nidx)[NN]    = (int (*)[NN])(smem + 67584);
  float* scratch       = (float*)(smem + 69632);
  float* dkp           = (float*)(smem + 77312);   // [16][45]
  float* kpl           = (float*)(smem + 80192);   // [45]

  const int tid = threadIdx.x;
  const int l = tid & 63, w = tid >> 6;
  const int pbase = blockIdx.x * 16;

  // phase 0a: neighbor indices + kernel points
  for (int t = tid; t < 512; t += 256) ((int*)nidx)[t] = nbr[(size_t)pbase * NN + t];
  if (tid < 45) kpl[tid] = Kp[tid];
  __syncthreads();
  // phase 0b: relative neighbor positions
  for (int t = tid; t < 512; t += 256) {
    int p = t >> 5, j = t & 31;
    int pj = nidx[p][j];
    dpos[p][j][0] = points[(size_t)pj * 3 + 0] - points[(size_t)(pbase + p) * 3 + 0];
    dpos[p][j][1] = points[(size_t)pj * 3 + 1] - points[(size_t)(pbase + p) * 3 + 1];
    dpos[p][j][2] = points[(size_t)pj * 3 + 2] - points[(size_t)(pbase + p) * 3 + 2];
  }
  __syncthreads();

  float* wIw = scratch + w * 480;

  // wf pass: gather nh, influence weights, wf -> A_lds (bf16, swizzled)
  auto wf_pass = [&](int pass) {
    for (int pi = 0; pi < 4; ++pi) {
      const int p = w * 4 + pi;
      u32 nhv[32];
#pragma unroll
      for (int j = 0; j < 32; ++j)
        nhv[j] = *(const u32*)(x1h + (size_t)nidx[p][j] * MID + 2 * l);
      // influence weights for this point
      const float* kps = pass ? (dkp + p * 45) : kpl;
#pragma unroll
      for (int it = 0; it < 8; ++it) {
        int idx = it * 64 + l;
        if (idx < 480) {
          int k = idx >> 5, j = idx & 31;
          float dx = dpos[p][j][0] - kps[k * 3 + 0];
          float dy = dpos[p][j][1] - kps[k * 3 + 1];
          float dz = dpos[p][j][2] - kps[k * 3 + 2];
          wIw[idx] = fmaxf(1.f - 2.f * sqrtf(dx * dx + dy * dy + dz * dz), 0.f);
        }
      }
      __syncthreads();
      float nhf0[32], nhf1[32];
#pragma unroll
      for (int j = 0; j < 32; ++j) {
        nhf0[j] = __builtin_bit_cast(float, nhv[j] << 16);
        nhf1[j] = __builtin_bit_cast(float, nhv[j] & 0xffff0000u);
      }
#pragma unroll
      for (int k = 0; k < NKP; ++k) {
        float a0 = 0.f, a1 = 0.f;
#pragma unroll
        for (int j = 0; j < 32; j += 4) {
          f32x4 wi = *(const f32x4*)(wIw + k * 32 + j);
          a0 += wi[0] * nhf0[j];     a1 += wi[0] * nhf1[j];
          a0 += wi[1] * nhf0[j + 1]; a1 += wi[1] * nhf1[j + 1];
          a0 += wi[2] * nhf0[j + 2]; a1 += wi[2] * nhf1[j + 2];
          a0 += wi[3] * nhf0[j + 3]; a1 += wi[3] * nhf1[j + 3];
        }
        int kcg = k * 16 + (l >> 2);           // kc = k*128 + 2l, kcg = kc>>3
        u32 pk = (u32)f2bf(a0) | ((u32)f2bf(a1) << 16);
        *(u32*)(smem + kcg * 256 + ((p ^ (kcg & 7)) << 4) + ((l & 3) << 2)) = pk;
      }
      __syncthreads();
    }
  };

  // phase 1: wf1 (rigid kernel points)
  wf_pass(0);

  // phase 2: offsets GEMM f0[16][48] = wf1 @ w0t^T  (waves 0..2, no barriers inside)
  if (w < 3) {
    f32x4 facc = {0.f, 0.f, 0.f, 0.f};
    const u16* brow = w0t + (size_t)(w * 16 + (l & 15)) * KTOT + (l >> 4) * 8;
    for (int s = 0; s < KSTEPS; ++s) {
      int kcg = s * 4 + (l >> 4);
      short8 av = *(const short8*)(smem + kcg * 256 + (((l & 15) ^ (kcg & 7)) << 4));
      short8 bv = *(const short8*)(brow + s * 32);
      facc = __builtin_amdgcn_mfma_f32_16x16x32_bf16(av, bv, facc, 0, 0, 0);
    }
    float* f0buf = scratch;  // [16][48] (aliases wI region; all waves past barrier)
#pragma unroll
    for (int q = 0; q < 4; ++q)
      f0buf[((l >> 4) * 4 + q) * 48 + w * 16 + (l & 15)] = facc[q];
  }
  __syncthreads();

  // phase 3: deformed kernel points dkp[p][k][r]
  for (int t = tid; t < 720; t += 256) {
    int p = t / 45, rem = t - p * 45;
    dkp[p * 45 + rem] = kpl[rem] + KP_EXTENT * (scratch[p * 48 + rem] + b0[rem]);
  }
  __syncthreads();

  // phase 4: wf2 (deformed kernel points)
  wf_pass(1);

  // phase 5: conv2 GEMM x2[16][128] = wf2 @ KVt^T (each wave: 2 cout tiles)
  {
    f32x4 acc0 = {0.f, 0.f, 0.f, 0.f}, acc1 = {0.f, 0.f, 0.f, 0.f};
    const u16* brow0 = KVt + (size_t)(w * 32 + (l & 15)) * KTOT + (l >> 4) * 8;
    const u16* brow1 = brow0 + (size_t)16 * KTOT;
    for (int s = 0; s < KSTEPS; ++s) {
      int kcg = s * 4 + (l >> 4);
      short8 av = *(const short8*)(smem + kcg * 256 + (((l & 15) ^ (kcg & 7)) << 4));
      short8 bv0 = *(const short8*)(brow0 + s * 32);
      short8 bv1 = *(const short8*)(brow1 + s * 32);
      acc0 = __builtin_amdgcn_mfma_f32_16x16x32_bf16(av, bv0, acc0, 0, 0, 0);
      acc1 = __builtin_amdgcn_mfma_f32_16x16x32_bf16(av, bv1, acc1, 0, 0, 0);
    }
#pragma unroll
    for (int q = 0; q < 4; ++q) {
      int p = (l >> 4) * 4 + q;
      size_t o = (size_t)(pbase + p) * MID + w * 32 + (l & 15);
      x2[o]      = lrelu(acc0[q]);
      x2[o + 16] = lrelu(acc1[q]);
    }
  }
}

// ---------------- K2: out = lrelu( lrelu(f@Ws) + lrelu(x2@W3) ), 8 rows/block ----------------
__global__ __launch_bounds__(512) void k_final(const float* __restrict__ x2,
                                               const float* __restrict__ feats,
                                               const float* __restrict__ W3,
                                               const float* __restrict__ Ws,
                                               float* __restrict__ out) {
  __shared__ float xs[8][MID];
  __shared__ float fs[8][INF];
  const int tid = threadIdx.x;
  const int base = blockIdx.x * 8;
  for (int t = tid; t < 8 * MID; t += 512) {
    int r = t >> 7, c = t & 127;
    xs[r][c] = x2[(size_t)(base + r) * MID + c];
  }
  for (int t = tid; t < 8 * INF; t += 512) {
    int r = t >> 8, c = t & 255;
    fs[r][c] = feats[(size_t)(base + r) * INF + c];
  }
  __syncthreads();
  float a3[8] = {0.f, 0.f, 0.f, 0.f, 0.f, 0.f, 0.f, 0.f};
  for (int k = 0; k < MID; ++k) {
    float wv = W3[k * OUTF + tid];
#pragma unroll
    for (int r = 0; r < 8; ++r) a3[r] += xs[r][k] * wv;
  }
  float as[8] = {0.f, 0.f, 0.f, 0.f, 0.f, 0.f, 0.f, 0.f};
  for (int k = 0; k < INF; ++k) {
    float wv = Ws[k * OUTF + tid];
#pragma unroll
    for (int r = 0; r < 8; ++r) as[r] += fs[r][k] * wv;
  }
#pragma unroll
  for (int r = 0; r < 8; ++r)
    out[(size_t)(base + r) * OUTF + tid] = lrelu(lrelu(as[r]) + lrelu(a3[r]));
}

extern "C" void kernel_launch(void* const* d_in, const int* in_sizes, int n_in,
                              void* d_out, int out_size, void* d_ws, size_t ws_size,
                              hipStream_t stream) {
  const float* points = (const float*)d_in[0];
  const float* feats  = (const float*)d_in[1];
  const int*   nbr    = (const int*)d_in[2];
  const float* W1     = (const float*)d_in[3];
  const float* W3     = (const float*)d_in[4];
  const float* Ws     = (const float*)d_in[5];
  const float* KV     = (const float*)d_in[6];
  const float* w0     = (const float*)d_in[7];
  const float* b0     = (const float*)d_in[8];
  const float* Kp     = (const float*)d_in[9];
  float* out = (float*)d_out;

  const int n = in_sizes[0] / 3;  // 20000
  // ws carving (16,035,840 B total, all 16B-aligned)
  float* x2  = (float*)d_ws;                              // [n][128] f32 = 10,240,000
  u16*   x1h = (u16*)((char*)d_ws + 10240000);            // [n][128] bf16 = 5,120,000
  u16*   KVt = (u16*)((char*)d_ws + 15360000);            // [128][1920] bf16 = 491,520
  u16*   w0t = (u16*)((char*)d_ws + 15851520);            // [48][1920] bf16 = 184,320

  k_cast  <<<120,    256, 0, stream>>>(KV, w0, KVt, w0t);
  k_conv1 <<<n / 8,  128, 0, stream>>>(feats, W1, x1h);
  k_deform<<<n / 16, 256, 0, stream>>>(points, nbr, x1h, Kp, w0t, b0, KVt, x2);
  k_final <<<n / 8,  512, 0, stream>>>(x2, feats, W3, Ws, out);
}

// Round 4
// 379.339 us; speedup vs baseline: 5.0758x; 1.3245x over previous
//
#include <hip/hip_runtime.h>
#include <hip/hip_bf16.h>

#define LRELU_SLOPE 0.1f
#define KP_EXTENT 0.5f
#define NKP 15
#define NN 32
#define INF 256
#define MID 128
#define OUTF 512
#define KTOT 1920   // NKP*MID
#define KSTEPS 60   // KTOT/32

typedef unsigned short u16;
typedef unsigned int   u32;
typedef __attribute__((ext_vector_type(8))) short short8;
typedef __attribute__((ext_vector_type(4))) float f32x4;
typedef __attribute__((ext_vector_type(4))) u32  u32x4;

__device__ __forceinline__ float lrelu(float x) { return x >= 0.f ? x : LRELU_SLOPE * x; }
__device__ __forceinline__ u16 f2bf(float f) {
  u32 u = __builtin_bit_cast(u32, f);
  u += 0x7fffu + ((u >> 16) & 1u);
  return (u16)(u >> 16);
}
__device__ __forceinline__ u32 pack2(float a, float b) {
  return (u32)f2bf(a) | ((u32)f2bf(b) << 16);
}

// ---------------- K_cast: bf16 transposed weights ----------------
// blocks 0..59: KV [1920][128] -> KVt [128][1920]
// blocks 60..119: w0 [1920][45] -> w0t [48][1920] (pad)
// blocks 120..151: Ws [256][512] -> Wst [512][256]
// blocks 152..167: W3 [128][512] -> W3t [512][128]
__global__ __launch_bounds__(256) void k_cast(const float* __restrict__ KV,
                                              const float* __restrict__ w0,
                                              const float* __restrict__ Ws,
                                              const float* __restrict__ W3,
                                              u16* __restrict__ KVt,
                                              u16* __restrict__ w0t,
                                              u16* __restrict__ Wst,
                                              u16* __restrict__ W3t) {
  __shared__ float tile[32][129];
  const int bx = blockIdx.x, tid = threadIdx.x;
  if (bx < 60) {
    const int kcb = bx * 32;
    for (int t = tid; t < 32 * 128; t += 256) {
      int kc = t >> 7, c = t & 127;
      tile[kc][c] = KV[(size_t)(kcb + kc) * 128 + c];
    }
    __syncthreads();
    for (int t = tid; t < 128 * 16; t += 256) {
      int c = t >> 4, kc = (t & 15) * 2;
      *(u32*)(KVt + (size_t)c * KTOT + kcb + kc) = pack2(tile[kc][c], tile[kc + 1][c]);
    }
  } else if (bx < 120) {
    const int kcb = (bx - 60) * 32;
    for (int t = tid; t < 32 * 45; t += 256) {
      int kc = t / 45, c = t - kc * 45;
      tile[kc][c] = w0[(size_t)(kcb + kc) * 45 + c];
    }
    __syncthreads();
    for (int t = tid; t < 48 * 16; t += 256) {
      int o = t >> 4, kc = (t & 15) * 2;
      float v0 = (o < 45) ? tile[kc][o] : 0.f;
      float v1 = (o < 45) ? tile[kc + 1][o] : 0.f;
      *(u32*)(w0t + (size_t)o * KTOT + kcb + kc) = pack2(v0, v1);
    }
  } else if (bx < 152) {
    const int b2 = bx - 120, kt = b2 >> 2, ct = b2 & 3;   // K=256: 8 ktiles, 4 ctiles
    for (int t = tid; t < 32 * 128; t += 256) {
      int kk = t >> 7, c = t & 127;
      tile[kk][c] = Ws[(size_t)(kt * 32 + kk) * OUTF + ct * 128 + c];
    }
    __syncthreads();
    for (int t = tid; t < 128 * 16; t += 256) {
      int c = t >> 4, kk = (t & 15) * 2;
      *(u32*)(Wst + (size_t)(ct * 128 + c) * INF + kt * 32 + kk) =
          pack2(tile[kk][c], tile[kk + 1][c]);
    }
  } else {
    const int b3 = bx - 152, kt = b3 >> 2, ct = b3 & 3;   // K=128: 4 ktiles, 4 ctiles
    for (int t = tid; t < 32 * 128; t += 256) {
      int kk = t >> 7, c = t & 127;
      tile[kk][c] = W3[(size_t)(kt * 32 + kk) * OUTF + ct * 128 + c];
    }
    __syncthreads();
    for (int t = tid; t < 128 * 16; t += 256) {
      int c = t >> 4, kk = (t & 15) * 2;
      *(u32*)(W3t + (size_t)(ct * 128 + c) * MID + kt * 32 + kk) =
          pack2(tile[kk][c], tile[kk + 1][c]);
    }
  }
}

// ---------------- K0: x1h = bf16(lrelu(features @ W1)) ----------------
__global__ __launch_bounds__(128) void k_conv1(const float* __restrict__ feats,
                                               const float* __restrict__ W1,
                                               u16* __restrict__ x1h) {
  __shared__ float sf[8][INF];
  const int tid = threadIdx.x;
  const int base = blockIdx.x * 8;
#pragma unroll
  for (int r = 0; r < 8; ++r) {
    sf[r][tid]       = feats[(size_t)(base + r) * INF + tid];
    sf[r][tid + 128] = feats[(size_t)(base + r) * INF + tid + 128];
  }
  __syncthreads();
  float acc[8] = {0.f, 0.f, 0.f, 0.f, 0.f, 0.f, 0.f, 0.f};
  for (int k = 0; k < INF; ++k) {
    float w = W1[k * MID + tid];
#pragma unroll
    for (int r = 0; r < 8; ++r) acc[r] += sf[r][k] * w;
  }
#pragma unroll
  for (int r = 0; r < 8; ++r)
    x1h[(size_t)(base + r) * MID + tid] = f2bf(lrelu(acc[r]));
}

// ---------------- K1: deformable KPConv, 16 points/block, all-MFMA ----------------
// LDS map (81908 B <= 81920, 2 blocks/CU):
//   A_LDS [0,61440)      : wf bf16 [kcg 240][slot 16][e 8], slot = p ^ (kcg&7)
//   NHT   [61440,71680)  : nhT[128 c][40 j] bf16 (pad 32->40; 80B rows, 16B-aligned)
//                          alias: f0buf [16][48] f32 (3072 B)
//   WI    [71680,72704)  : wI[16 kp][32 j] bf16
//   DPOS  [72704,78848)  : f32 [16][32][3]
//   DKP   [78848,81728)  : f32 [16][45]
//   KPL   [81728,81908)  : f32 [45]
#define A_LDS 0
#define NHT   61440
#define WI    71680
#define DPOS  72704
#define DKP   78848
#define KPL   81728

__global__ __launch_bounds__(256, 2) void k_deform(const float* __restrict__ points,
                                                   const int*  __restrict__ nbr,
                                                   const u16*  __restrict__ x1h,
                                                   const float* __restrict__ Kp,
                                                   const u16*  __restrict__ w0t,
                                                   const float* __restrict__ b0,
                                                   const u16*  __restrict__ KVt,
                                                   u16* __restrict__ x2h) {
  __shared__ __align__(16) char smem[81920];
  float (*dpos)[NN][3] = (float (*)[NN][3])(smem + DPOS);
  float* dkp = (float*)(smem + DKP);
  float* kpl = (float*)(smem + KPL);

  const int tid = threadIdx.x;
  const int l = tid & 63, w = tid >> 6;
  const int pbase = blockIdx.x * 16;

  // phase 0: kernel points + relative neighbor positions
  if (tid < 45) kpl[tid] = Kp[tid];
  for (int t = tid; t < 512; t += 256) {
    int p = t >> 5, j = t & 31;
    int pj = nbr[(size_t)(pbase + p) * NN + j];
    dpos[p][j][0] = points[(size_t)pj * 3 + 0] - points[(size_t)(pbase + p) * 3 + 0];
    dpos[p][j][1] = points[(size_t)pj * 3 + 1] - points[(size_t)(pbase + p) * 3 + 1];
    dpos[p][j][2] = points[(size_t)pj * 3 + 2] - points[(size_t)(pbase + p) * 3 + 2];
  }
  __syncthreads();

  // one pass = for each of 16 points: gather nh -> nhT, wI, 8 MFMAs -> A_lds
  auto wf_pass = [&](int pass) {
    for (int p = 0; p < 16; ++p) {
      // issue gathers (regs): wave w covers channels 32w..32w+31 of all 32 rows
      const int j = l >> 1;
      const int pj = nbr[(size_t)(pbase + p) * NN + j];
      const u16* src = x1h + (size_t)pj * MID + w * 32 + (l & 1) * 8;
      short8 ga = *(const short8*)(src);
      short8 gb = *(const short8*)(src + 16);
      // compute wI values into regs (reads dpos/dkp, stable)
      float wv0 = 0.f, wv1 = 0.f;
      const int idx = tid * 2;
      int kp_ = 0, j_ = 0;
      if (idx < 480) {
        kp_ = idx >> 5; j_ = idx & 31;
        const float* kps = pass ? (dkp + p * 45 + kp_ * 3) : (kpl + kp_ * 3);
        float kx = kps[0], ky = kps[1], kz = kps[2];
        float dx0 = dpos[p][j_][0] - kx, dy0 = dpos[p][j_][1] - ky, dz0 = dpos[p][j_][2] - kz;
        float dx1 = dpos[p][j_ + 1][0] - kx, dy1 = dpos[p][j_ + 1][1] - ky, dz1 = dpos[p][j_ + 1][2] - kz;
        wv0 = fmaxf(1.f - 2.f * sqrtf(dx0 * dx0 + dy0 * dy0 + dz0 * dz0), 0.f);
        wv1 = fmaxf(1.f - 2.f * sqrtf(dx1 * dx1 + dy1 * dy1 + dz1 * dz1), 0.f);
      }
      __syncthreads();   // previous point's MFMA done reading nhT/wI
      // transposed nh writes: nhT[ch][j], rows padded to 40 elems (80 B)
      {
        const int ch0 = w * 32 + (l & 1) * 8;
#pragma unroll
        for (int e = 0; e < 8; ++e)
          *(u16*)(smem + NHT + (ch0 + e) * 80 + (j << 1)) = (u16)ga[e];
#pragma unroll
        for (int e = 0; e < 8; ++e)
          *(u16*)(smem + NHT + (ch0 + 16 + e) * 80 + (j << 1)) = (u16)gb[e];
      }
      if (idx < 480) {
        *(u32*)(smem + WI + kp_ * 64 + (j_ << 1)) = pack2(wv0, wv1);
      } else if (tid < 256) {   // zero kp row 15 (bytes 960..1023)
        *(u32*)(smem + WI + 960 + (tid - 240) * 4) = 0u;
      }
      __syncthreads();   // nhT/wI visible
      // 8 MFMAs across 4 waves: wf[16kp][128c] for this point
      {
        short8 av = *(const short8*)(smem + WI + (l & 15) * 64 + (l >> 4) * 16);
#pragma unroll
        for (int c = 0; c < 2; ++c) {
          const int ct = w * 2 + c;
          short8 bv = *(const short8*)(smem + NHT + (ct * 16 + (l & 15)) * 80 + (l >> 4) * 16);
          f32x4 d = {0.f, 0.f, 0.f, 0.f};
          d = __builtin_amdgcn_mfma_f32_16x16x32_bf16(av, bv, d, 0, 0, 0);
#pragma unroll
          for (int q = 0; q < 4; ++q) {
            const int kp = (l >> 4) * 4 + q;
            if (kp < NKP) {
              const int kc = kp * 128 + ct * 16 + (l & 15);
              const int kcg = kc >> 3;
              *(u16*)(smem + A_LDS + kcg * 256 + ((p ^ (kcg & 7)) << 4) + (kc & 7) * 2) =
                  f2bf(d[q]);
            }
          }
        }
      }
    }
    __syncthreads();   // A_lds complete; nhT free
  };

  // pass 1: rigid kernel points
  wf_pass(0);

  // phase 2: f0[16][48] = wf1 @ w0t^T (waves 0..2)
  if (w < 3) {
    f32x4 facc = {0.f, 0.f, 0.f, 0.f};
    const u16* brow = w0t + (size_t)(w * 16 + (l & 15)) * KTOT + (l >> 4) * 8;
    for (int s = 0; s < KSTEPS; ++s) {
      int kcg = s * 4 + (l >> 4);
      short8 av = *(const short8*)(smem + A_LDS + kcg * 256 + (((l & 15) ^ (kcg & 7)) << 4));
      short8 bv = *(const short8*)(brow + s * 32);
      facc = __builtin_amdgcn_mfma_f32_16x16x32_bf16(av, bv, facc, 0, 0, 0);
    }
    float* f0buf = (float*)(smem + NHT);   // [16][48]
#pragma unroll
    for (int q = 0; q < 4; ++q)
      f0buf[((l >> 4) * 4 + q) * 48 + w * 16 + (l & 15)] = facc[q];
  }
  __syncthreads();

  // phase 3: deformed kernel points
  {
    const float* f0buf = (const float*)(smem + NHT);
    for (int t = tid; t < 720; t += 256) {
      int p = t / 45, rem = t - p * 45;
      dkp[p * 45 + rem] = kpl[rem] + KP_EXTENT * (f0buf[p * 48 + rem] + b0[rem]);
    }
  }
  __syncthreads();

  // pass 2: deformed kernel points
  wf_pass(1);

  // phase 5: x2[16][128] = wf2 @ KVt^T -> bf16
  {
    f32x4 acc0 = {0.f, 0.f, 0.f, 0.f}, acc1 = {0.f, 0.f, 0.f, 0.f};
    const u16* brow0 = KVt + (size_t)(w * 32 + (l & 15)) * KTOT + (l >> 4) * 8;
    const u16* brow1 = brow0 + (size_t)16 * KTOT;
    for (int s = 0; s < KSTEPS; ++s) {
      int kcg = s * 4 + (l >> 4);
      short8 av = *(const short8*)(smem + A_LDS + kcg * 256 + (((l & 15) ^ (kcg & 7)) << 4));
      short8 bv0 = *(const short8*)(brow0 + s * 32);
      short8 bv1 = *(const short8*)(brow1 + s * 32);
      acc0 = __builtin_amdgcn_mfma_f32_16x16x32_bf16(av, bv0, acc0, 0, 0, 0);
      acc1 = __builtin_amdgcn_mfma_f32_16x16x32_bf16(av, bv1, acc1, 0, 0, 0);
    }
#pragma unroll
    for (int q = 0; q < 4; ++q) {
      int p = (l >> 4) * 4 + q;
      size_t o = (size_t)(pbase + p) * MID + w * 32 + (l & 15);
      x2h[o]      = f2bf(lrelu(acc0[q]));
      x2h[o + 16] = f2bf(lrelu(acc1[q]));
    }
  }
}

// ---------------- K2: out = lrelu(lrelu(f@Ws) + lrelu(x2@W3)), MFMA ----------------
__global__ __launch_bounds__(256, 2) void k_final(const u16* __restrict__ x2h,
                                                  const float* __restrict__ feats,
                                                  const u16* __restrict__ Wst,
                                                  const u16* __restrict__ W3t,
                                                  float* __restrict__ out) {
  __shared__ __align__(16) char fsm[48 * 256];   // A_lds [48 kcg][16 slot][8] bf16
  const int tid = threadIdx.x;
  const int l = tid & 63, w = tid >> 6;
  const int base = blockIdx.x * 16;

  // stage feats (f32 -> bf16) into kcg 0..31
  for (int t = tid; t < 512; t += 256) {
    int p = t >> 5, kcg = t & 31;
    f32x4 a = *(const f32x4*)(feats + (size_t)(base + p) * INF + kcg * 8);
    f32x4 b = *(const f32x4*)(feats + (size_t)(base + p) * INF + kcg * 8 + 4);
    u32x4 pk = {pack2(a[0], a[1]), pack2(a[2], a[3]), pack2(b[0], b[1]), pack2(b[2], b[3])};
    *(u32x4*)(fsm + kcg * 256 + ((p ^ (kcg & 7)) << 4)) = pk;
  }
  // stage x2h into kcg 32..47
  {
    int p = tid >> 4, kcg = 32 + (tid & 15);
    short8 v = *(const short8*)(x2h + (size_t)(base + p) * MID + (tid & 15) * 8);
    *(short8*)(fsm + kcg * 256 + ((p ^ (kcg & 7)) << 4)) = v;
  }
  __syncthreads();

  f32x4 accS[8], acc3[8];
#pragma unroll
  for (int ct = 0; ct < 8; ++ct) {
    accS[ct] = {0.f, 0.f, 0.f, 0.f};
    acc3[ct] = {0.f, 0.f, 0.f, 0.f};
  }
  for (int s = 0; s < 8; ++s) {   // shortcut: K = 256 over Wst
    int kcg = s * 4 + (l >> 4);
    short8 av = *(const short8*)(fsm + kcg * 256 + (((l & 15) ^ (kcg & 7)) << 4));
#pragma unroll
    for (int ct = 0; ct < 8; ++ct) {
      int cout = w * 128 + ct * 16 + (l & 15);
      short8 bv = *(const short8*)(Wst + (size_t)cout * INF + s * 32 + (l >> 4) * 8);
      accS[ct] = __builtin_amdgcn_mfma_f32_16x16x32_bf16(av, bv, accS[ct], 0, 0, 0);
    }
  }
  for (int s = 8; s < 12; ++s) {  // conv3: K = 128 over W3t
    int kcg = s * 4 + (l >> 4);
    short8 av = *(const short8*)(fsm + kcg * 256 + (((l & 15) ^ (kcg & 7)) << 4));
#pragma unroll
    for (int ct = 0; ct < 8; ++ct) {
      int cout = w * 128 + ct * 16 + (l & 15);
      short8 bv = *(const short8*)(W3t + (size_t)cout * MID + (s - 8) * 32 + (l >> 4) * 8);
      acc3[ct] = __builtin_amdgcn_mfma_f32_16x16x32_bf16(av, bv, acc3[ct], 0, 0, 0);
    }
  }
#pragma unroll
  for (int ct = 0; ct < 8; ++ct) {
#pragma unroll
    for (int q = 0; q < 4; ++q) {
      int p = (l >> 4) * 4 + q;
      out[(size_t)(base + p) * OUTF + w * 128 + ct * 16 + (l & 15)] =
          lrelu(lrelu(accS[ct][q]) + lrelu(acc3[ct][q]));
    }
  }
}

extern "C" void kernel_launch(void* const* d_in, const int* in_sizes, int n_in,
                              void* d_out, int out_size, void* d_ws, size_t ws_size,
                              hipStream_t stream) {
  const float* points = (const float*)d_in[0];
  const float* feats  = (const float*)d_in[1];
  const int*   nbr    = (const int*)d_in[2];
  const float* W1     = (const float*)d_in[3];
  const float* W3     = (const float*)d_in[4];
  const float* Ws     = (const float*)d_in[5];
  const float* KV     = (const float*)d_in[6];
  const float* w0     = (const float*)d_in[7];
  const float* b0     = (const float*)d_in[8];
  const float* Kp     = (const float*)d_in[9];
  float* out = (float*)d_out;

  const int n = in_sizes[0] / 3;  // 20000
  // ws carving (11,309,056 B, all 16B-aligned)
  u16* x1h = (u16*)d_ws;                                   // [n][128] bf16 = 5,120,000
  u16* x2h = (u16*)((char*)d_ws + 5120000);                // [n][128] bf16 = 5,120,000
  u16* KVt = (u16*)((char*)d_ws + 10240000);               // [128][1920] = 491,520
  u16* w0t = (u16*)((char*)d_ws + 10731520);               // [48][1920]  = 184,320
  u16* Wst = (u16*)((char*)d_ws + 10915840);               // [512][256]  = 262,144
  u16* W3t = (u16*)((char*)d_ws + 11177984);               // [512][128]  = 131,072

  k_cast  <<<168,    256, 0, stream>>>(KV, w0, Ws, W3, KVt, w0t, Wst, W3t);
  k_conv1 <<<n / 8,  128, 0, stream>>>(feats, W1, x1h);
  k_deform<<<n / 16, 256, 0, stream>>>(points, nbr, x1h, Kp, w0t, b0, KVt, x2h);
  k_final <<<n / 16, 256, 0, stream>>>(x2h, feats, Wst, W3t, out);
}

// Round 7
// 305.784 us; speedup vs baseline: 6.2968x; 1.2405x over previous
//
#include <hip/hip_runtime.h>
#include <hip/hip_bf16.h>

#define LRELU_SLOPE 0.1f
#define KP_EXTENT 0.5f
#define NKP 15
#define NN 32
#define INF 256
#define MID 128
#define OUTF 512
#define KTOT 1920   // NKP*MID
#define KSTEPS 60   // KTOT/32

typedef unsigned short u16;
typedef unsigned int   u32;
typedef __attribute__((ext_vector_type(8))) short short8;
typedef __attribute__((ext_vector_type(4))) float f32x4;
typedef __attribute__((ext_vector_type(4))) u32  u32x4;

__device__ __forceinline__ float lrelu(float x) { return x >= 0.f ? x : LRELU_SLOPE * x; }
__device__ __forceinline__ u16 f2bf(float f) {
  u32 u = __builtin_bit_cast(u32, f);
  u += 0x7fffu + ((u >> 16) & 1u);
  return (u16)(u >> 16);
}
__device__ __forceinline__ u32 pack2(float a, float b) {
  return (u32)f2bf(a) | ((u32)f2bf(b) << 16);
}

// ---------------- K_cast: bf16 transposed weights ----------------
// 0..59: KV->KVt[128][1920]; 60..119: w0->w0t[48][1920];
// 120..151: Ws->Wst[512][256]; 152..167: W3->W3t[512][128]; 168..175: W1->W1t[128][256]
__global__ __launch_bounds__(256) void k_cast(const float* __restrict__ KV,
                                              const float* __restrict__ w0,
                                              const float* __restrict__ Ws,
                                              const float* __restrict__ W3,
                                              const float* __restrict__ W1,
                                              u16* __restrict__ KVt,
                                              u16* __restrict__ w0t,
                                              u16* __restrict__ Wst,
                                              u16* __restrict__ W3t,
                                              u16* __restrict__ W1t) {
  __shared__ float tile[32][129];
  const int bx = blockIdx.x, tid = threadIdx.x;
  if (bx < 60) {
    const int kcb = bx * 32;
    for (int t = tid; t < 32 * 128; t += 256) {
      int kc = t >> 7, c = t & 127;
      tile[kc][c] = KV[(size_t)(kcb + kc) * 128 + c];
    }
    __syncthreads();
    for (int t = tid; t < 128 * 16; t += 256) {
      int c = t >> 4, kc = (t & 15) * 2;
      *(u32*)(KVt + (size_t)c * KTOT + kcb + kc) = pack2(tile[kc][c], tile[kc + 1][c]);
    }
  } else if (bx < 120) {
    const int kcb = (bx - 60) * 32;
    for (int t = tid; t < 32 * 45; t += 256) {
      int kc = t / 45, c = t - kc * 45;
      tile[kc][c] = w0[(size_t)(kcb + kc) * 45 + c];
    }
    __syncthreads();
    for (int t = tid; t < 48 * 16; t += 256) {
      int o = t >> 4, kc = (t & 15) * 2;
      float v0 = (o < 45) ? tile[kc][o] : 0.f;
      float v1 = (o < 45) ? tile[kc + 1][o] : 0.f;
      *(u32*)(w0t + (size_t)o * KTOT + kcb + kc) = pack2(v0, v1);
    }
  } else if (bx < 152) {
    const int b2 = bx - 120, kt = b2 >> 2, ct = b2 & 3;
    for (int t = tid; t < 32 * 128; t += 256) {
      int kk = t >> 7, c = t & 127;
      tile[kk][c] = Ws[(size_t)(kt * 32 + kk) * OUTF + ct * 128 + c];
    }
    __syncthreads();
    for (int t = tid; t < 128 * 16; t += 256) {
      int c = t >> 4, kk = (t & 15) * 2;
      *(u32*)(Wst + (size_t)(ct * 128 + c) * INF + kt * 32 + kk) =
          pack2(tile[kk][c], tile[kk + 1][c]);
    }
  } else if (bx < 168) {
    const int b3 = bx - 152, kt = b3 >> 2, ct = b3 & 3;
    for (int t = tid; t < 32 * 128; t += 256) {
      int kk = t >> 7, c = t & 127;
      tile[kk][c] = W3[(size_t)(kt * 32 + kk) * OUTF + ct * 128 + c];
    }
    __syncthreads();
    for (int t = tid; t < 128 * 16; t += 256) {
      int c = t >> 4, kk = (t & 15) * 2;
      *(u32*)(W3t + (size_t)(ct * 128 + c) * MID + kt * 32 + kk) =
          pack2(tile[kk][c], tile[kk + 1][c]);
    }
  } else {
    const int kt = bx - 168;                       // W1 [256][128] -> W1t [128][256]
    for (int t = tid; t < 32 * 128; t += 256) {
      int kk = t >> 7, c = t & 127;
      tile[kk][c] = W1[(size_t)(kt * 32 + kk) * MID + c];
    }
    __syncthreads();
    for (int t = tid; t < 128 * 16; t += 256) {
      int c = t >> 4, kk = (t & 15) * 2;
      *(u32*)(W1t + (size_t)c * INF + kt * 32 + kk) =
          pack2(tile[kk][c], tile[kk + 1][c]);
    }
  }
}

// ---------------- K0: x1h = bf16(lrelu(feats @ W1)), MFMA, 16 rows/block ----------------
__global__ __launch_bounds__(256, 2) void k_conv1(const float* __restrict__ feats,
                                                  const u16* __restrict__ W1t,
                                                  u16* __restrict__ x1h) {
  __shared__ __align__(16) char fsm[32 * 256];   // [32 kcg][16 slot][8] bf16
  const int tid = threadIdx.x;
  const int l = tid & 63, w = tid >> 6;
  const int base = blockIdx.x * 16;

  for (int t = tid; t < 512; t += 256) {
    int p = t >> 5, kcg = t & 31;
    f32x4 a = *(const f32x4*)(feats + (size_t)(base + p) * INF + kcg * 8);
    f32x4 b = *(const f32x4*)(feats + (size_t)(base + p) * INF + kcg * 8 + 4);
    u32x4 pk = {pack2(a[0], a[1]), pack2(a[2], a[3]), pack2(b[0], b[1]), pack2(b[2], b[3])};
    *(u32x4*)(fsm + kcg * 256 + ((p ^ (kcg & 7)) << 4)) = pk;
  }
  __syncthreads();

  f32x4 acc0 = {0.f, 0.f, 0.f, 0.f}, acc1 = {0.f, 0.f, 0.f, 0.f};
  for (int s = 0; s < 8; ++s) {
    int kcg = s * 4 + (l >> 4);
    short8 av = *(const short8*)(fsm + kcg * 256 + (((l & 15) ^ (kcg & 7)) << 4));
    short8 bv0 = *(const short8*)(W1t + (size_t)(w * 32 + (l & 15)) * INF + s * 32 + (l >> 4) * 8);
    short8 bv1 = *(const short8*)(W1t + (size_t)(w * 32 + 16 + (l & 15)) * INF + s * 32 + (l >> 4) * 8);
    acc0 = __builtin_amdgcn_mfma_f32_16x16x32_bf16(av, bv0, acc0, 0, 0, 0);
    acc1 = __builtin_amdgcn_mfma_f32_16x16x32_bf16(av, bv1, acc1, 0, 0, 0);
  }
#pragma unroll
  for (int q = 0; q < 4; ++q) {
    int p = (l >> 4) * 4 + q;
    size_t o = (size_t)(base + p) * MID + w * 32 + (l & 15);
    x1h[o]      = f2bf(lrelu(acc0[q]));
    x1h[o + 16] = f2bf(lrelu(acc1[q]));
  }
}

// ---------------- K1: deformable KPConv, 16 points/block, barrier-free wf ----------------
// LDS map (75776 B, 2 blocks/CU):
//   A_LDS [0,61440)       : wf bf16 [kcg 240][slot 16][e 8], slot = p ^ (kcg&7)
//   F0BUF [61440,64512)   : f32 [16][48]
//   DPOS  [64512,70656)   : f32 [16][32][3]
//   NIDX  [70656,72704)   : i32 [16][32]
//   DKP   [72704,75584)   : f32 [16][45]
//   KPL   [75584,75776)   : f32 [45]
#define A_LDS 0
#define F0BUF 61440
#define DPOS  64512
#define NIDX  70656
#define DKP   72704
#define KPL   75584

__global__ __launch_bounds__(256, 2) void k_deform(const float* __restrict__ points,
                                                   const int*  __restrict__ nbr,
                                                   const u16*  __restrict__ x1h,
                                                   const float* __restrict__ Kp,
                                                   const u16*  __restrict__ w0t,
                                                   const float* __restrict__ b0,
                                                   const u16*  __restrict__ KVt,
                                                   u16* __restrict__ x2h) {
  __shared__ __align__(16) char smem[75776];
  float (*dpos)[NN][3] = (float (*)[NN][3])(smem + DPOS);
  int   (*nidx)[NN]    = (int (*)[NN])(smem + NIDX);
  float* dkp = (float*)(smem + DKP);
  float* kpl = (float*)(smem + KPL);

  const int tid = threadIdx.x;
  const int l = tid & 63, w = tid >> 6;
  const int g = l >> 4, li = l & 15, j8 = g * 8;
  const int pbase = blockIdx.x * 16;

  // phase 0: kernel points + neighbor idx + relative positions (single barrier)
  if (tid < 45) kpl[tid] = Kp[tid];
  for (int t = tid; t < 512; t += 256) {
    int p = t >> 5, j = t & 31;
    int pj = nbr[(size_t)(pbase + p) * NN + j];
    nidx[p][j] = pj;
    dpos[p][j][0] = points[(size_t)pj * 3 + 0] - points[(size_t)(pbase + p) * 3 + 0];
    dpos[p][j][1] = points[(size_t)pj * 3 + 1] - points[(size_t)(pbase + p) * 3 + 1];
    dpos[p][j][2] = points[(size_t)pj * 3 + 2] - points[(size_t)(pbase + p) * 3 + 2];
  }
  __syncthreads();

  // wf pass: per wave, 4 points, no barriers. B-frag gathered to regs, wI in-lane.
  auto wf_pass = [&](int pass) {
    for (int pi = 0; pi < 4; ++pi) {
      const int p = w * 4 + pi;
      int rows[8];
#pragma unroll
      for (int e = 0; e < 8; ++e) rows[e] = nidx[p][j8 + e];
      short8 bv[8];
#pragma unroll
      for (int e = 0; e < 8; ++e) {
        const u16* src = x1h + (size_t)rows[e] * MID + li;
#pragma unroll
        for (int ct = 0; ct < 8; ++ct) bv[ct][e] = (short)src[ct * 16];
      }
      // wI A-fragment: kp = li, j = j8+e
      const int kp = (li < 15) ? li : 0;
      const float* kps = pass ? (dkp + p * 45 + kp * 3) : (kpl + kp * 3);
      const float kx = kps[0], ky = kps[1], kz = kps[2];
      short8 av;
#pragma unroll
      for (int e = 0; e < 8; ++e) {
        const int j = j8 + e;
        float dx = dpos[p][j][0] - kx;
        float dy = dpos[p][j][1] - ky;
        float dz = dpos[p][j][2] - kz;
        float wv = fmaxf(1.f - 2.f * sqrtf(dx * dx + dy * dy + dz * dz), 0.f);
        av[e] = (short)f2bf((li < 15) ? wv : 0.f);
      }
#pragma unroll
      for (int ct = 0; ct < 8; ++ct) {
        f32x4 d = {0.f, 0.f, 0.f, 0.f};
        d = __builtin_amdgcn_mfma_f32_16x16x32_bf16(av, bv[ct], d, 0, 0, 0);
#pragma unroll
        for (int q = 0; q < 4; ++q) {
          const int kpq = g * 4 + q;
          if (kpq < NKP) {
            const int kc = kpq * 128 + ct * 16 + li;
            const int kcg = kc >> 3;
            *(u16*)(smem + A_LDS + kcg * 256 + ((p ^ (kcg & 7)) << 4) + (kc & 7) * 2) =
                f2bf(d[q]);
          }
        }
      }
    }
    __syncthreads();
  };

  // pass 1: rigid kernel points
  wf_pass(0);

  // phase 2: f0[16][48] = wf1 @ w0t^T (waves 0..2)
  if (w < 3) {
    f32x4 facc = {0.f, 0.f, 0.f, 0.f};
    const u16* brow = w0t + (size_t)(w * 16 + li) * KTOT + g * 8;
    for (int s = 0; s < KSTEPS; ++s) {
      int kcg = s * 4 + g;
      short8 av = *(const short8*)(smem + A_LDS + kcg * 256 + ((li ^ (kcg & 7)) << 4));
      short8 bv = *(const short8*)(brow + s * 32);
      facc = __builtin_amdgcn_mfma_f32_16x16x32_bf16(av, bv, facc, 0, 0, 0);
    }
    float* f0buf = (float*)(smem + F0BUF);
#pragma unroll
    for (int q = 0; q < 4; ++q)
      f0buf[(g * 4 + q) * 48 + w * 16 + li] = facc[q];
  }
  __syncthreads();

  // phase 3: deformed kernel points
  {
    const float* f0buf = (const float*)(smem + F0BUF);
    for (int t = tid; t < 720; t += 256) {
      int p = t / 45, rem = t - p * 45;
      dkp[p * 45 + rem] = kpl[rem] + KP_EXTENT * (f0buf[p * 48 + rem] + b0[rem]);
    }
  }
  __syncthreads();

  // pass 2: deformed kernel points
  wf_pass(1);

  // phase 5: x2[16][128] = wf2 @ KVt^T -> bf16
  {
    f32x4 acc0 = {0.f, 0.f, 0.f, 0.f}, acc1 = {0.f, 0.f, 0.f, 0.f};
    const u16* brow0 = KVt + (size_t)(w * 32 + li) * KTOT + g * 8;
    const u16* brow1 = brow0 + (size_t)16 * KTOT;
    for (int s = 0; s < KSTEPS; ++s) {
      int kcg = s * 4 + g;
      short8 av = *(const short8*)(smem + A_LDS + kcg * 256 + ((li ^ (kcg & 7)) << 4));
      short8 bv0 = *(const short8*)(brow0 + s * 32);
      short8 bv1 = *(const short8*)(brow1 + s * 32);
      acc0 = __builtin_amdgcn_mfma_f32_16x16x32_bf16(av, bv0, acc0, 0, 0, 0);
      acc1 = __builtin_amdgcn_mfma_f32_16x16x32_bf16(av, bv1, acc1, 0, 0, 0);
    }
#pragma unroll
    for (int q = 0; q < 4; ++q) {
      int p = g * 4 + q;
      size_t o = (size_t)(pbase + p) * MID + w * 32 + li;
      x2h[o]      = f2bf(lrelu(acc0[q]));
      x2h[o + 16] = f2bf(lrelu(acc1[q]));
    }
  }
}

// ---------------- K2: out = lrelu(lrelu(f@Ws) + lrelu(x2@W3)), MFMA ----------------
__global__ __launch_bounds__(256, 2) void k_final(const u16* __restrict__ x2h,
                                                  const float* __restrict__ feats,
                                                  const u16* __restrict__ Wst,
                                                  const u16* __restrict__ W3t,
                                                  float* __restrict__ out) {
  __shared__ __align__(16) char fsm[48 * 256];   // [48 kcg][16 slot][8] bf16
  const int tid = threadIdx.x;
  const int l = tid & 63, w = tid >> 6;
  const int base = blockIdx.x * 16;

  for (int t = tid; t < 512; t += 256) {
    int p = t >> 5, kcg = t & 31;
    f32x4 a = *(const f32x4*)(feats + (size_t)(base + p) * INF + kcg * 8);
    f32x4 b = *(const f32x4*)(feats + (size_t)(base + p) * INF + kcg * 8 + 4);
    u32x4 pk = {pack2(a[0], a[1]), pack2(a[2], a[3]), pack2(b[0], b[1]), pack2(b[2], b[3])};
    *(u32x4*)(fsm + kcg * 256 + ((p ^ (kcg & 7)) << 4)) = pk;
  }
  {
    int p = tid >> 4, kcg = 32 + (tid & 15);
    short8 v = *(const short8*)(x2h + (size_t)(base + p) * MID + (tid & 15) * 8);
    *(short8*)(fsm + kcg * 256 + ((p ^ (kcg & 7)) << 4)) = v;
  }
  __syncthreads();

  f32x4 accS[8], acc3[8];
#pragma unroll
  for (int ct = 0; ct < 8; ++ct) {
    accS[ct] = {0.f, 0.f, 0.f, 0.f};
    acc3[ct] = {0.f, 0.f, 0.f, 0.f};
  }
  for (int s = 0; s < 8; ++s) {
    int kcg = s * 4 + (l >> 4);
    short8 av = *(const short8*)(fsm + kcg * 256 + (((l & 15) ^ (kcg & 7)) << 4));
#pragma unroll
    for (int ct = 0; ct < 8; ++ct) {
      int cout = w * 128 + ct * 16 + (l & 15);
      short8 bv = *(const short8*)(Wst + (size_t)cout * INF + s * 32 + (l >> 4) * 8);
      accS[ct] = __builtin_amdgcn_mfma_f32_16x16x32_bf16(av, bv, accS[ct], 0, 0, 0);
    }
  }
  for (int s = 8; s < 12; ++s) {
    int kcg = s * 4 + (l >> 4);
    short8 av = *(const short8*)(fsm + kcg * 256 + (((l & 15) ^ (kcg & 7)) << 4));
#pragma unroll
    for (int ct = 0; ct < 8; ++ct) {
      int cout = w * 128 + ct * 16 + (l & 15);
      short8 bv = *(const short8*)(W3t + (size_t)cout * MID + (s - 8) * 32 + (l >> 4) * 8);
      acc3[ct] = __builtin_amdgcn_mfma_f32_16x16x32_bf16(av, bv, acc3[ct], 0, 0, 0);
    }
  }
#pragma unroll
  for (int ct = 0; ct < 8; ++ct) {
#pragma unroll
    for (int q = 0; q < 4; ++q) {
      int p = (l >> 4) * 4 + q;
      out[(size_t)(base + p) * OUTF + w * 128 + ct * 16 + (l & 15)] =
          lrelu(lrelu(accS[ct][q]) + lrelu(acc3[ct][q]));
    }
  }
}

extern "C" void kernel_launch(void* const* d_in, const int* in_sizes, int n_in,
                              void* d_out, int out_size, void* d_ws, size_t ws_size,
                              hipStream_t stream) {
  const float* points = (const float*)d_in[0];
  const float* feats  = (const float*)d_in[1];
  const int*   nbr    = (const int*)d_in[2];
  const float* W1     = (const float*)d_in[3];
  const float* W3     = (const float*)d_in[4];
  const float* Ws     = (const float*)d_in[5];
  const float* KV     = (const float*)d_in[6];
  const float* w0     = (const float*)d_in[7];
  const float* b0     = (const float*)d_in[8];
  const float* Kp     = (const float*)d_in[9];
  float* out = (float*)d_out;

  const int n = in_sizes[0] / 3;  // 20000
  // ws carving (11,374,592 B, 16B-aligned)
  u16* x1h = (u16*)d_ws;                                   // [n][128]    = 5,120,000
  u16* x2h = (u16*)((char*)d_ws + 5120000);                // [n][128]    = 5,120,000
  u16* KVt = (u16*)((char*)d_ws + 10240000);               // [128][1920] = 491,520
  u16* w0t = (u16*)((char*)d_ws + 10731520);               // [48][1920]  = 184,320
  u16* Wst = (u16*)((char*)d_ws + 10915840);               // [512][256]  = 262,144
  u16* W3t = (u16*)((char*)d_ws + 11177984);               // [512][128]  = 131,072
  u16* W1t = (u16*)((char*)d_ws + 11309056);               // [128][256]  = 65,536

  k_cast  <<<176,    256, 0, stream>>>(KV, w0, Ws, W3, W1, KVt, w0t, Wst, W3t, W1t);
  k_conv1 <<<n / 16, 256, 0, stream>>>(feats, W1t, x1h);
  k_deform<<<n / 16, 256, 0, stream>>>(points, nbr, x1h, Kp, w0t, b0, KVt, x2h);
  k_final <<<n / 16, 256, 0, stream>>>(x2h, feats, Wst, W3t, out);
}

// Round 9
// 299.297 us; speedup vs baseline: 6.4333x; 1.0217x over previous
//
#include <hip/hip_runtime.h>
#include <hip/hip_bf16.h>

#define LRELU_SLOPE 0.1f
#define KP_EXTENT 0.5f
#define NKP 15
#define NN 32
#define INF 256
#define MID 128
#define OUTF 512
#define KTOT 1920   // NKP*MID
#define KSTEPS 60   // KTOT/32

typedef unsigned short u16;
typedef unsigned int   u32;
typedef __attribute__((ext_vector_type(8))) short short8;
typedef __attribute__((ext_vector_type(4))) float f32x4;
typedef __attribute__((ext_vector_type(4))) u32  u32x4;

__device__ __forceinline__ float lrelu(float x) { return x >= 0.f ? x : LRELU_SLOPE * x; }
__device__ __forceinline__ u16 f2bf(float f) {
  u32 u = __builtin_bit_cast(u32, f);
  u += 0x7fffu + ((u >> 16) & 1u);
  return (u16)(u >> 16);
}
__device__ __forceinline__ u32 pack2(float a, float b) {
  return (u32)f2bf(a) | ((u32)f2bf(b) << 16);
}

// ---------------- K_cast: bf16 transposed weights ----------------
// 0..59: KV->KVt[128][1920]; 60..119: w0->w0t[48][1920];
// 120..151: Ws->Wst[512][256]; 152..167: W3->W3t[512][128]; 168..175: W1->W1t[128][256]
__global__ __launch_bounds__(256) void k_cast(const float* __restrict__ KV,
                                              const float* __restrict__ w0,
                                              const float* __restrict__ Ws,
                                              const float* __restrict__ W3,
                                              const float* __restrict__ W1,
                                              u16* __restrict__ KVt,
                                              u16* __restrict__ w0t,
                                              u16* __restrict__ Wst,
                                              u16* __restrict__ W3t,
                                              u16* __restrict__ W1t) {
  __shared__ float tile[32][129];
  const int bx = blockIdx.x, tid = threadIdx.x;
  if (bx < 60) {
    const int kcb = bx * 32;
    for (int t = tid; t < 32 * 128; t += 256) {
      int kc = t >> 7, c = t & 127;
      tile[kc][c] = KV[(size_t)(kcb + kc) * 128 + c];
    }
    __syncthreads();
    for (int t = tid; t < 128 * 16; t += 256) {
      int c = t >> 4, kc = (t & 15) * 2;
      *(u32*)(KVt + (size_t)c * KTOT + kcb + kc) = pack2(tile[kc][c], tile[kc + 1][c]);
    }
  } else if (bx < 120) {
    const int kcb = (bx - 60) * 32;
    for (int t = tid; t < 32 * 45; t += 256) {
      int kc = t / 45, c = t - kc * 45;
      tile[kc][c] = w0[(size_t)(kcb + kc) * 45 + c];
    }
    __syncthreads();
    for (int t = tid; t < 48 * 16; t += 256) {
      int o = t >> 4, kc = (t & 15) * 2;
      float v0 = (o < 45) ? tile[kc][o] : 0.f;
      float v1 = (o < 45) ? tile[kc + 1][o] : 0.f;
      *(u32*)(w0t + (size_t)o * KTOT + kcb + kc) = pack2(v0, v1);
    }
  } else if (bx < 152) {
    const int b2 = bx - 120, kt = b2 >> 2, ct = b2 & 3;
    for (int t = tid; t < 32 * 128; t += 256) {
      int kk = t >> 7, c = t & 127;
      tile[kk][c] = Ws[(size_t)(kt * 32 + kk) * OUTF + ct * 128 + c];
    }
    __syncthreads();
    for (int t = tid; t < 128 * 16; t += 256) {
      int c = t >> 4, kk = (t & 15) * 2;
      *(u32*)(Wst + (size_t)(ct * 128 + c) * INF + kt * 32 + kk) =
          pack2(tile[kk][c], tile[kk + 1][c]);
    }
  } else if (bx < 168) {
    const int b3 = bx - 152, kt = b3 >> 2, ct = b3 & 3;
    for (int t = tid; t < 32 * 128; t += 256) {
      int kk = t >> 7, c = t & 127;
      tile[kk][c] = W3[(size_t)(kt * 32 + kk) * OUTF + ct * 128 + c];
    }
    __syncthreads();
    for (int t = tid; t < 128 * 16; t += 256) {
      int c = t >> 4, kk = (t & 15) * 2;
      *(u32*)(W3t + (size_t)(ct * 128 + c) * MID + kt * 32 + kk) =
          pack2(tile[kk][c], tile[kk + 1][c]);
    }
  } else {
    const int kt = bx - 168;                       // W1 [256][128] -> W1t [128][256]
    for (int t = tid; t < 32 * 128; t += 256) {
      int kk = t >> 7, c = t & 127;
      tile[kk][c] = W1[(size_t)(kt * 32 + kk) * MID + c];
    }
    __syncthreads();
    for (int t = tid; t < 128 * 16; t += 256) {
      int c = t >> 4, kk = (t & 15) * 2;
      *(u32*)(W1t + (size_t)c * INF + kt * 32 + kk) =
          pack2(tile[kk][c], tile[kk + 1][c]);
    }
  }
}

// ---------------- K0: x1h = bf16(lrelu(feats @ W1)), MFMA, 16 rows/block ----------------
__global__ __launch_bounds__(256, 2) void k_conv1(const float* __restrict__ feats,
                                                  const u16* __restrict__ W1t,
                                                  u16* __restrict__ x1h) {
  __shared__ __align__(16) char fsm[32 * 256];   // [32 kcg][16 slot][8] bf16
  const int tid = threadIdx.x;
  const int l = tid & 63, w = tid >> 6;
  const int base = blockIdx.x * 16;

  for (int t = tid; t < 512; t += 256) {
    int p = t >> 5, kcg = t & 31;
    f32x4 a = *(const f32x4*)(feats + (size_t)(base + p) * INF + kcg * 8);
    f32x4 b = *(const f32x4*)(feats + (size_t)(base + p) * INF + kcg * 8 + 4);
    u32x4 pk = {pack2(a[0], a[1]), pack2(a[2], a[3]), pack2(b[0], b[1]), pack2(b[2], b[3])};
    *(u32x4*)(fsm + kcg * 256 + ((p ^ (kcg & 7)) << 4)) = pk;
  }
  __syncthreads();

  f32x4 acc0 = {0.f, 0.f, 0.f, 0.f}, acc1 = {0.f, 0.f, 0.f, 0.f};
  for (int s = 0; s < 8; ++s) {
    int kcg = s * 4 + (l >> 4);
    short8 av = *(const short8*)(fsm + kcg * 256 + (((l & 15) ^ (kcg & 7)) << 4));
    short8 bv0 = *(const short8*)(W1t + (size_t)(w * 32 + (l & 15)) * INF + s * 32 + (l >> 4) * 8);
    short8 bv1 = *(const short8*)(W1t + (size_t)(w * 32 + 16 + (l & 15)) * INF + s * 32 + (l >> 4) * 8);
    acc0 = __builtin_amdgcn_mfma_f32_16x16x32_bf16(av, bv0, acc0, 0, 0, 0);
    acc1 = __builtin_amdgcn_mfma_f32_16x16x32_bf16(av, bv1, acc1, 0, 0, 0);
  }
#pragma unroll
  for (int q = 0; q < 4; ++q) {
    int p = (l >> 4) * 4 + q;
    size_t o = (size_t)(base + p) * MID + w * 32 + (l & 15);
    x1h[o]      = f2bf(lrelu(acc0[q]));
    x1h[o + 16] = f2bf(lrelu(acc1[q]));
  }
}

// ---------------- K1: deformable KPConv, 16 points/block, barrier-free wf ----------------
// LDS map (75776 B, 2 blocks/CU):
//   A_LDS [0,61440)       : wf bf16 [kcg 240][slot 16][e 8], slot = p ^ (kcg&7)
//   F0BUF [61440,64512)   : f32 [16][48]
//   DPOS  [64512,70656)   : f32 [16][32][3]
//   NIDX  [70656,72704)   : i32 [16][32]
//   DKP   [72704,75584)   : f32 [16][45]
//   KPL   [75584,75776)   : f32 [45]
#define A_LDS 0
#define F0BUF 61440
#define DPOS  64512
#define NIDX  70656
#define DKP   72704
#define KPL   75584

__global__ __launch_bounds__(256, 2) void k_deform(const float* __restrict__ points,
                                                   const int*  __restrict__ nbr,
                                                   const u16*  __restrict__ x1h,
                                                   const float* __restrict__ Kp,
                                                   const u16*  __restrict__ w0t,
                                                   const float* __restrict__ b0,
                                                   const u16*  __restrict__ KVt,
                                                   u16* __restrict__ x2h) {
  __shared__ __align__(16) char smem[75776];
  float (*dpos)[NN][3] = (float (*)[NN][3])(smem + DPOS);
  int   (*nidx)[NN]    = (int (*)[NN])(smem + NIDX);
  float* dkp = (float*)(smem + DKP);
  float* kpl = (float*)(smem + KPL);

  const int tid = threadIdx.x;
  const int l = tid & 63, w = tid >> 6;
  const int g = l >> 4, li = l & 15, j8 = g * 8;
  const int pbase = blockIdx.x * 16;

  // phase 0: kernel points + neighbor idx + relative positions (single barrier)
  if (tid < 45) kpl[tid] = Kp[tid];
  for (int t = tid; t < 512; t += 256) {
    int p = t >> 5, j = t & 31;
    int pj = nbr[(size_t)(pbase + p) * NN + j];
    nidx[p][j] = pj;
    dpos[p][j][0] = points[(size_t)pj * 3 + 0] - points[(size_t)(pbase + p) * 3 + 0];
    dpos[p][j][1] = points[(size_t)pj * 3 + 1] - points[(size_t)(pbase + p) * 3 + 1];
    dpos[p][j][2] = points[(size_t)pj * 3 + 2] - points[(size_t)(pbase + p) * 3 + 2];
  }
  __syncthreads();

  // wf pass: per wave, 4 points, no barriers.
  // B-tile ct covers channels {n*8+ct}: gather = one 16B load/row, wf store = ds_write_b128.
  auto wf_pass = [&](int pass) {
    for (int pi = 0; pi < 4; ++pi) {
      const int p = w * 4 + pi;
      // 8 coalesced row loads: ve[e] = x1h[nidx[p][j8+e]][li*8 .. +8)
      u32 ve[8][4];
#pragma unroll
      for (int e = 0; e < 8; ++e) {
        const int row = nidx[p][j8 + e];
        u32x4 t = *(const u32x4*)(x1h + (size_t)row * MID + li * 8);
        ve[e][0] = t[0]; ve[e][1] = t[1]; ve[e][2] = t[2]; ve[e][3] = t[3];
      }
      // wI A-fragment: kp = li, j = j8+e (in-lane)
      const int kp = (li < 15) ? li : 0;
      const float* kps = pass ? (dkp + p * 45 + kp * 3) : (kpl + kp * 3);
      const float kx = kps[0], ky = kps[1], kz = kps[2];
      short8 av;
#pragma unroll
      for (int e = 0; e < 8; ++e) {
        const int j = j8 + e;
        float dx = dpos[p][j][0] - kx;
        float dy = dpos[p][j][1] - ky;
        float dz = dpos[p][j][2] - kz;
        float wv = fmaxf(1.f - 2.f * sqrtf(dx * dx + dy * dy + dz * dz), 0.f);
        av[e] = (short)f2bf((li < 15) ? wv : 0.f);
      }
      // 8x8 u16 register transpose via v_perm: bv[ct][e] = ve[e][ct]
      short8 bv[8];
#pragma unroll
      for (int ct = 0; ct < 8; ++ct) {
        const u32 sel = (ct & 1) ? 0x07060302u : 0x05040100u;
        const int r = ct >> 1;
        u32 c0 = __builtin_amdgcn_perm(ve[1][r], ve[0][r], sel);
        u32 c1 = __builtin_amdgcn_perm(ve[3][r], ve[2][r], sel);
        u32 c2 = __builtin_amdgcn_perm(ve[5][r], ve[4][r], sel);
        u32 c3 = __builtin_amdgcn_perm(ve[7][r], ve[6][r], sel);
        bv[ct] = __builtin_bit_cast(short8, (u32x4){c0, c1, c2, c3});
      }
      // 8 independent MFMAs: wf[16kp][channels n*8+ct]
      f32x4 acc[8];
#pragma unroll
      for (int ct = 0; ct < 8; ++ct) {
        f32x4 z = {0.f, 0.f, 0.f, 0.f};
        acc[ct] = __builtin_amdgcn_mfma_f32_16x16x32_bf16(av, bv[ct], z, 0, 0, 0);
      }
      // store: per q one ds_write_b128 (kc = kp*128 + li*8 + ct -> kcg = kp*16+li, e = ct)
#pragma unroll
      for (int q = 0; q < 4; ++q) {
        const int kpq = g * 4 + q;
        if (kpq < NKP) {
          u32x4 o = {pack2(acc[0][q], acc[1][q]), pack2(acc[2][q], acc[3][q]),
                     pack2(acc[4][q], acc[5][q]), pack2(acc[6][q], acc[7][q])};
          const int kcg = kpq * 16 + li;
          *(u32x4*)(smem + A_LDS + kcg * 256 + ((p ^ (li & 7)) << 4)) = o;
        }
      }
    }
    __syncthreads();
  };

  // pass 1: rigid kernel points
  wf_pass(0);

  // phase 2: f0[16][48] = wf1 @ w0t^T (waves 0..2)
  if (w < 3) {
    f32x4 facc = {0.f, 0.f, 0.f, 0.f};
    const u16* brow = w0t + (size_t)(w * 16 + li) * KTOT + g * 8;
    for (int s = 0; s < KSTEPS; ++s) {
      int kcg = s * 4 + g;
      short8 av = *(const short8*)(smem + A_LDS + kcg * 256 + ((li ^ (kcg & 7)) << 4));
      short8 bv = *(const short8*)(brow + s * 32);
      facc = __builtin_amdgcn_mfma_f32_16x16x32_bf16(av, bv, facc, 0, 0, 0);
    }
    float* f0buf = (float*)(smem + F0BUF);
#pragma unroll
    for (int q = 0; q < 4; ++q)
      f0buf[(g * 4 + q) * 48 + w * 16 + li] = facc[q];
  }
  __syncthreads();

  // phase 3: deformed kernel points
  {
    const float* f0buf = (const float*)(smem + F0BUF);
    for (int t = tid; t < 720; t += 256) {
      int p = t / 45, rem = t - p * 45;
      dkp[p * 45 + rem] = kpl[rem] + KP_EXTENT * (f0buf[p * 48 + rem] + b0[rem]);
    }
  }
  __syncthreads();

  // pass 2: deformed kernel points
  wf_pass(1);

  // phase 5: x2[16][128] = wf2 @ KVt^T -> bf16
  {
    f32x4 acc0 = {0.f, 0.f, 0.f, 0.f}, acc1 = {0.f, 0.f, 0.f, 0.f};
    const u16* brow0 = KVt + (size_t)(w * 32 + li) * KTOT + g * 8;
    const u16* brow1 = brow0 + (size_t)16 * KTOT;
    for (int s = 0; s < KSTEPS; ++s) {
      int kcg = s * 4 + g;
      short8 av = *(const short8*)(smem + A_LDS + kcg * 256 + ((li ^ (kcg & 7)) << 4));
      short8 bv0 = *(const short8*)(brow0 + s * 32);
      short8 bv1 = *(const short8*)(brow1 + s * 32);
      acc0 = __builtin_amdgcn_mfma_f32_16x16x32_bf16(av, bv0, acc0, 0, 0, 0);
      acc1 = __builtin_amdgcn_mfma_f32_16x16x32_bf16(av, bv1, acc1, 0, 0, 0);
    }
#pragma unroll
    for (int q = 0; q < 4; ++q) {
      int p = g * 4 + q;
      size_t o = (size_t)(pbase + p) * MID + w * 32 + li;
      x2h[o]      = f2bf(lrelu(acc0[q]));
      x2h[o + 16] = f2bf(lrelu(acc1[q]));
    }
  }
}

// ---------------- K2: out = lrelu(lrelu(f@Ws) + lrelu(x2@W3)), MFMA ----------------
__global__ __launch_bounds__(256, 2) void k_final(const u16* __restrict__ x2h,
                                                  const float* __restrict__ feats,
                                                  const u16* __restrict__ Wst,
                                                  const u16* __restrict__ W3t,
                                                  float* __restrict__ out) {
  __shared__ __align__(16) char fsm[48 * 256];   // [48 kcg][16 slot][8] bf16
  const int tid = threadIdx.x;
  const int l = tid & 63, w = tid >> 6;
  const int base = blockIdx.x * 16;

  for (int t = tid; t < 512; t += 256) {
    int p = t >> 5, kcg = t & 31;
    f32x4 a = *(const f32x4*)(feats + (size_t)(base + p) * INF + kcg * 8);
    f32x4 b = *(const f32x4*)(feats + (size_t)(base + p) * INF + kcg * 8 + 4);
    u32x4 pk = {pack2(a[0], a[1]), pack2(a[2], a[3]), pack2(b[0], b[1]), pack2(b[2], b[3])};
    *(u32x4*)(fsm + kcg * 256 + ((p ^ (kcg & 7)) << 4)) = pk;
  }
  {
    int p = tid >> 4, kcg = 32 + (tid & 15);
    short8 v = *(const short8*)(x2h + (size_t)(base + p) * MID + (tid & 15) * 8);
    *(short8*)(fsm + kcg * 256 + ((p ^ (kcg & 7)) << 4)) = v;
  }
  __syncthreads();

  f32x4 accS[8], acc3[8];
#pragma unroll
  for (int ct = 0; ct < 8; ++ct) {
    accS[ct] = {0.f, 0.f, 0.f, 0.f};
    acc3[ct] = {0.f, 0.f, 0.f, 0.f};
  }
  for (int s = 0; s < 8; ++s) {
    int kcg = s * 4 + (l >> 4);
    short8 av = *(const short8*)(fsm + kcg * 256 + (((l & 15) ^ (kcg & 7)) << 4));
#pragma unroll
    for (int ct = 0; ct < 8; ++ct) {
      int cout = w * 128 + ct * 16 + (l & 15);
      short8 bv = *(const short8*)(Wst + (size_t)cout * INF + s * 32 + (l >> 4) * 8);
      accS[ct] = __builtin_amdgcn_mfma_f32_16x16x32_bf16(av, bv, accS[ct], 0, 0, 0);
    }
  }
  for (int s = 8; s < 12; ++s) {
    int kcg = s * 4 + (l >> 4);
    short8 av = *(const short8*)(fsm + kcg * 256 + (((l & 15) ^ (kcg & 7)) << 4));
#pragma unroll
    for (int ct = 0; ct < 8; ++ct) {
      int cout = w * 128 + ct * 16 + (l & 15);
      short8 bv = *(const short8*)(W3t + (size_t)cout * MID + (s - 8) * 32 + (l >> 4) * 8);
      acc3[ct] = __builtin_amdgcn_mfma_f32_16x16x32_bf16(av, bv, acc3[ct], 0, 0, 0);
    }
  }
#pragma unroll
  for (int ct = 0; ct < 8; ++ct) {
#pragma unroll
    for (int q = 0; q < 4; ++q) {
      int p = (l >> 4) * 4 + q;
      out[(size_t)(base + p) * OUTF + w * 128 + ct * 16 + (l & 15)] =
          lrelu(lrelu(accS[ct][q]) + lrelu(acc3[ct][q]));
    }
  }
}

extern "C" void kernel_launch(void* const* d_in, const int* in_sizes, int n_in,
                              void* d_out, int out_size, void* d_ws, size_t ws_size,
                              hipStream_t stream) {
  const float* points = (const float*)d_in[0];
  const float* feats  = (const float*)d_in[1];
  const int*   nbr    = (const int*)d_in[2];
  const float* W1     = (const float*)d_in[3];
  const float* W3     = (const float*)d_in[4];
  const float* Ws     = (const float*)d_in[5];
  const float* KV     = (const float*)d_in[6];
  const float* w0     = (const float*)d_in[7];
  const float* b0     = (const float*)d_in[8];
  const float* Kp     = (const float*)d_in[9];
  float* out = (float*)d_out;

  const int n = in_sizes[0] / 3;  // 20000
  // ws carving (11,374,592 B, 16B-aligned)
  u16* x1h = (u16*)d_ws;                                   // [n][128]    = 5,120,000
  u16* x2h = (u16*)((char*)d_ws + 5120000);                // [n][128]    = 5,120,000
  u16* KVt = (u16*)((char*)d_ws + 10240000);               // [128][1920] = 491,520
  u16* w0t = (u16*)((char*)d_ws + 10731520);               // [48][1920]  = 184,320
  u16* Wst = (u16*)((char*)d_ws + 10915840);               // [512][256]  = 262,144
  u16* W3t = (u16*)((char*)d_ws + 11177984);               // [512][128]  = 131,072
  u16* W1t = (u16*)((char*)d_ws + 11309056);               // [128][256]  = 65,536

  k_cast  <<<176,    256, 0, stream>>>(KV, w0, Ws, W3, W1, KVt, w0t, Wst, W3t, W1t);
  k_conv1 <<<n / 16, 256, 0, stream>>>(feats, W1t, x1h);
  k_deform<<<n / 16, 256, 0, stream>>>(points, nbr, x1h, Kp, w0t, b0, KVt, x2h);
  k_final <<<n / 16, 256, 0, stream>>>(x2h, feats, Wst, W3t, out);
}